// Round 1
// baseline (70.321 us; speedup 1.0000x reference)
//
#include <hip/hip_runtime.h>
#include <math.h>

#define B_   16384
#define C_   256
#define N_   128
#define M_   20
#define S_   3
#define EMIT_ 26

// One block per batch row b. 128 threads = 2 waves; thread t owns output slot n=t.
__global__ __launch_bounds__(128) void ntm_fused_kernel(
    const float* __restrict__ ctrl,    // (B, C)
    const float* __restrict__ w_prev,  // (B, N)
    const float* __restrict__ Mt,      // (B, N, M)
    const float* __restrict__ W,       // (C, EMIT)
    const float* __restrict__ bvec,    // (EMIT)
    float* __restrict__ out)           // (B, N)
{
    const int b    = blockIdx.x;
    const int t    = threadIdx.x;
    const int lane = t & 63;
    const int wid  = t >> 6;

    __shared__ float c_lds[C_];
    __shared__ float fc_lds[32];
    __shared__ float wg_lds[N_];
    __shared__ float rbuf[2];   // softmax max
    __shared__ float rbuf2[2];  // softmax sum
    __shared__ float rbuf3[2];  // final norm sum

    // ---- load controller row into LDS (coalesced) ----
    const float* crow = ctrl + (size_t)b * C_;
    c_lds[t]       = crow[t];
    c_lds[t + 128] = crow[t + 128];
    __syncthreads();

    // ---- fc = tanh(c @ W + b): j = t>>2 (use j<26), q = t&3 sums 64 elems ----
    {
        const int j = t >> 2, q = t & 3;
        float a0 = 0.f, a1 = 0.f;
        if (j < EMIT_) {
            const int i0 = q * 64;
            #pragma unroll
            for (int i = 0; i < 64; i += 2) {
                a0 = fmaf(c_lds[i0 + i],     W[(size_t)(i0 + i)     * EMIT_ + j], a0);
                a1 = fmaf(c_lds[i0 + i + 1], W[(size_t)(i0 + i + 1) * EMIT_ + j], a1);
            }
        }
        float acc = a0 + a1;
        acc += __shfl_xor(acc, 1);   // combine the 4-lane group
        acc += __shfl_xor(acc, 2);
        if (q == 0 && j < EMIT_) fc_lds[j] = tanhf(acc + bvec[j]);
    }
    __syncthreads();

    // ---- per-thread head parameters (broadcast reads from LDS) ----
    float k[M_];
    float ksq = 0.f;
    #pragma unroll
    for (int m = 0; m < M_; ++m) { k[m] = fc_lds[m]; ksq = fmaf(k[m], k[m], ksq); }

    const float beta  = log1pf(__expf(fc_lds[20]));          // softplus; arg in (-1,1): safe
    const float g     = 1.f / (1.f + __expf(-fc_lds[21]));   // sigmoid
    const float e0 = __expf(fc_lds[22]);
    const float e1 = __expf(fc_lds[23]);
    const float e2 = __expf(fc_lds[24]);
    const float einv = 1.f / (e0 + e1 + e2);
    const float s0 = e0 * einv, s1 = e1 * einv, s2 = e2 * einv;
    const float gamma = 1.f + log1pf(__expf(fc_lds[25]));

    // ---- cosine similarity logits: thread t handles memory row n = t ----
    const float* Mrow = Mt + ((size_t)b * N_ + t) * M_;
    float dot = 0.f, msq = 0.f;
    #pragma unroll
    for (int i = 0; i < 5; ++i) {
        float4 v = *(const float4*)(Mrow + 4 * i);
        dot = fmaf(k[4*i+0], v.x, dot);  msq = fmaf(v.x, v.x, msq);
        dot = fmaf(k[4*i+1], v.y, dot);  msq = fmaf(v.y, v.y, msq);
        dot = fmaf(k[4*i+2], v.z, dot);  msq = fmaf(v.z, v.z, msq);
        dot = fmaf(k[4*i+3], v.w, dot);  msq = fmaf(v.w, v.w, msq);
    }
    const float logit = beta * dot / sqrtf(ksq * msq);

    // ---- softmax over n (block-wide: wave shuffle reduce + 2-wave LDS combine) ----
    float mx = logit;
    #pragma unroll
    for (int o = 32; o; o >>= 1) mx = fmaxf(mx, __shfl_xor(mx, o));
    if (lane == 0) rbuf[wid] = mx;
    __syncthreads();
    mx = fmaxf(rbuf[0], rbuf[1]);

    const float e = __expf(logit - mx);
    float sm = e;
    #pragma unroll
    for (int o = 32; o; o >>= 1) sm += __shfl_xor(sm, o);
    if (lane == 0) rbuf2[wid] = sm;
    __syncthreads();
    sm = rbuf2[0] + rbuf2[1];

    const float w_c = e / sm;

    // ---- interpolate with previous weights ----
    const float w_g = g * w_c + (1.f - g) * w_prev[(size_t)b * N_ + t];
    wg_lds[t] = w_g;
    __syncthreads();

    // ---- circular convolution shift (S=3): w~[n] = wg[n+1]*s0 + wg[n]*s1 + wg[n-1]*s2 ----
    const float wt_ = wg_lds[(t + 1) & (N_ - 1)] * s0
                    + w_g * s1
                    + wg_lds[(t + N_ - 1) & (N_ - 1)] * s2;

    // ---- sharpen: w^gamma, then normalize ----
    const float wr = (wt_ > 0.f) ? __expf(gamma * __logf(wt_)) : 0.f;

    float ssum = wr;
    #pragma unroll
    for (int o = 32; o; o >>= 1) ssum += __shfl_xor(ssum, o);
    if (lane == 0) rbuf3[wid] = ssum;
    __syncthreads();
    const float total = rbuf3[0] + rbuf3[1];

    out[(size_t)b * N_ + t] = wr / total;
}

extern "C" void kernel_launch(void* const* d_in, const int* in_sizes, int n_in,
                              void* d_out, int out_size, void* d_ws, size_t ws_size,
                              hipStream_t stream) {
    const float* ctrl   = (const float*)d_in[0];
    const float* w_prev = (const float*)d_in[1];
    const float* Mt     = (const float*)d_in[2];
    const float* W      = (const float*)d_in[3];
    const float* bvec   = (const float*)d_in[4];
    float* out = (float*)d_out;

    ntm_fused_kernel<<<dim3(B_), dim3(128), 0, stream>>>(ctrl, w_prev, Mt, W, bvec, out);
}